// Round 4
// baseline (228.539 us; speedup 1.0000x reference)
//
#include <hip/hip_runtime.h>
#include <math.h>

#define NB 128
#define NT 512
#define NEDIM 128
#define NNEG 64
#define SCHUNK 32
#define NBLK (NB * (NT / SCHUNK))   // 2048 partial-sum slots

typedef __bf16 bf16x8 __attribute__((ext_vector_type(8)));
typedef float  f32x4  __attribute__((ext_vector_type(4)));

// Semi-persistent: 1024 blocks, each owns 2 consecutive s-chunks of the SAME b
// (pair 2p,2p+1 never straddles a 16-chunk group). Negatives staged once per
// block. Per tile: M=128 rows (m=4*s_local+(i-1)) x N=64 negs x K=128 (e),
// bf16 MFMA from xor-swizzled fragment-linear LDS. One ws write per tile,
// no same-address atomics (R2 post-mortem: ~5K one-dword atomics = ~90 us).
__launch_bounds__(256, 3)
__global__ void cpc_mfma_kernel(const float* __restrict__ base,        // (B,T,E)
                                const float* __restrict__ mce,         // (B,T,E,K)
                                const int*  __restrict__ seq_lens,     // (B)
                                const int*  __restrict__ sample_ids,   // (B,NNEG)
                                float* __restrict__ ws)                // (NBLK)
{
    const int j  = blockIdx.x;       // 0..1023
    const int b  = j >> 3;           // 8 blocks per b, consecutive -> L2 locality
    const int c0 = (j & 7) * 2;      // first chunk of the pair
    const int L  = seq_lens[b];
    const float LOG65 = 4.1743873f;
    const float wgt[4] = {1.f/261632.f, 1.f/261120.f, 1.f/260608.f, 1.f/260096.f};

    const int tid  = threadIdx.x;
    const int lane = tid & 63;
    const int w    = tid >> 6;
    const int q    = lane >> 4;
    const int fl   = lane & 15;

    // masked-chunk analytic contribution (all-zero ce rows -> loss = ln(65))
    auto masked_const = [&](int s0) {
        float c = 0.f;
        #pragma unroll
        for (int i = 1; i <= 4; ++i) {
            int hi = min(SCHUNK, (NT - i) - s0);
            if (hi > 0) c += (float)hi * LOG65 * wgt[i - 1];
        }
        return c;
    };

    // Both tiles masked: two scalar writes, exit before staging anything.
    if (c0 * SCHUNK >= L) {
        if (tid == 0) {
            ws[b * 16 + c0]     = masked_const(c0 * SCHUNK);
            ws[b * 16 + c0 + 1] = masked_const((c0 + 1) * SCHUNK);
        }
        return;
    }

    __shared__ __bf16 Afrag[2048 * 8];   // 2048 chunks x 16B
    __shared__ __bf16 Bfrag[1024 * 8];   // 1024 chunks x 16B
    __shared__ float  pos_lds[128];
    __shared__ float  wsum[4];

    const float4* mce4 = (const float4*)mce;   // (b*NT+s)*NEDIM + e -> 4 k values

    // ---- stage B once per block: gather negatives, bf16, fragment-linear ----
    {
        int n = tid & 63;
        int r = sample_ids[b * NNEG + n];
        const float4* srcb = (const float4*)(base + (size_t)r * NEDIM);
        int eb0 = (tid >> 6) * 4;
        #pragma unroll
        for (int it = 0; it < 4; ++it) {
            int eb = eb0 + it;
            float4 v0 = srcb[eb * 2], v1 = srcb[eb * 2 + 1];
            const float* f0 = (const float*)&v0;
            const float* f1 = (const float*)&v1;
            bf16x8 o;
            #pragma unroll
            for (int u = 0; u < 4; ++u) { o[u] = (__bf16)f0[u]; o[4 + u] = (__bf16)f1[u]; }
            *(bf16x8*)(&Bfrag[(eb * 64 + n) * 8]) = o;
        }
    }

    for (int t = 0; t < 2; ++t) {
        const int c    = c0 + t;
        const int s0   = c * SCHUNK;
        const int slot = b * 16 + c;

        if (s0 >= L) {                       // block-uniform; no barrier inside
            if (tid == 0) ws[slot] = masked_const(s0);
            continue;
        }

        // ---- stage A: transpose k->row, f32->bf16, fragment-linear chunks ----
        // chunk id = (kstep*8 + mt)*64 + q*16 + flm ; phys = chunk ^ ((chunk>>6)&7)
        #pragma unroll
        for (int it = 0; it < 2; ++it) {
            int g  = tid + 256 * it;          // 0..511 : (s, e-block)
            int s  = g & 31;
            int eb = g >> 5;                  // e0 = eb*8
            const float4* src = mce4 + (size_t)(b * NT + s0 + s) * NEDIM + eb * 8;
            float4 v[8];
            #pragma unroll
            for (int u = 0; u < 8; ++u) v[u] = src[u];
            const float* vf = (const float*)v;
            int Cs = (eb >> 2) * 8 + (s >> 2);
            int base_chunk = Cs * 64 + (eb & 3) * 16 + (s & 3) * 4;
            int x = Cs & 7;
            #pragma unroll
            for (int k = 0; k < 4; ++k) {
                int phys = (base_chunk + k) ^ x;
                bf16x8 o;
                #pragma unroll
                for (int u = 0; u < 8; ++u) o[u] = (__bf16)vf[4 * u + k];
                *(bf16x8*)(&Afrag[phys * 8]) = o;
            }
        }
        __syncthreads();                      // A (and B on first tile) visible

        // ---- MFMA: wave w owns M-tiles {2w,2w+1} x all 4 N-tiles ----
        f32x4 acc[2][4];
        #pragma unroll
        for (int mtl = 0; mtl < 2; ++mtl)
            #pragma unroll
            for (int nt = 0; nt < 4; ++nt) acc[mtl][nt] = (f32x4){0.f, 0.f, 0.f, 0.f};

        #pragma unroll
        for (int kstep = 0; kstep < 4; ++kstep) {
            bf16x8 af[2];
            #pragma unroll
            for (int mtl = 0; mtl < 2; ++mtl) {
                int Cs = kstep * 8 + (2 * w + mtl);
                int phys = (Cs * 64 + lane) ^ (Cs & 7);
                af[mtl] = *(const bf16x8*)(&Afrag[phys * 8]);
            }
            bf16x8 bv[4];
            #pragma unroll
            for (int nt = 0; nt < 4; ++nt) {
                int cB = (kstep * 4 + q) * 64 + nt * 16 + fl;
                bv[nt] = *(const bf16x8*)(&Bfrag[cB * 8]);
            }
            #pragma unroll
            for (int mtl = 0; mtl < 2; ++mtl)
                #pragma unroll
                for (int nt = 0; nt < 4; ++nt)
                    acc[mtl][nt] = __builtin_amdgcn_mfma_f32_16x16x32_bf16(
                        af[mtl], bv[nt], acc[mtl][nt], 0, 0, 0);
        }

        // ---- positives: pos[m] = sum_e A[m][e] * base[b][s+i][e] ----
        {
            int m    = tid >> 1;
            int eh   = tid & 1;              // e-half
            int sloc = m >> 2, ip = (m & 3) + 1;
            int srow = s0 + sloc + ip; if (srow > NT - 1) srow = NT - 1;  // clamp; invalid rows excluded later
            const float4* brow4 = (const float4*)(base + (size_t)(b * NT + srow) * NEDIM + eh * 64);
            int mt = m >> 4, flm = m & 15;
            float psum = 0.f;
            #pragma unroll
            for (int el = 0; el < 8; ++el) {
                int eb = eh * 8 + el;
                int Cs = (eb >> 2) * 8 + mt;
                int phys = (Cs * 64 + (eb & 3) * 16 + flm) ^ (Cs & 7);
                bf16x8 av = *(const bf16x8*)(&Afrag[phys * 8]);
                float4 b0 = brow4[el * 2], b1 = brow4[el * 2 + 1];
                const float* f0 = (const float*)&b0;
                const float* f1 = (const float*)&b1;
                #pragma unroll
                for (int u = 0; u < 4; ++u) {
                    psum = fmaf((float)av[u],     f0[u], psum);
                    psum = fmaf((float)av[4 + u], f1[u], psum);
                }
            }
            psum += __shfl_xor(psum, 1);
            if (eh == 0) pos_lds[m] = psum;
        }
        __syncthreads();

        // ---- epilogue: logsumexp over 65 logits per row, masked mean ----
        float lossacc = 0.f;
        #pragma unroll
        for (int mtl = 0; mtl < 2; ++mtl) {
            #pragma unroll
            for (int r = 0; r < 4; ++r) {
                int m  = w * 32 + mtl * 16 + q * 4 + r;    // C layout: row=(lane>>4)*4+reg
                int sg = s0 + (m >> 2);
                int ip = (m & 3) + 1;
                float z0 = acc[mtl][0][r], z1 = acc[mtl][1][r];
                float z2 = acc[mtl][2][r], z3 = acc[mtl][3][r];
                float p  = pos_lds[m];
                float mx = fmaxf(fmaxf(z0, z1), fmaxf(z2, z3));
                mx = fmaxf(mx, __shfl_xor(mx, 1));
                mx = fmaxf(mx, __shfl_xor(mx, 2));
                mx = fmaxf(mx, __shfl_xor(mx, 4));
                mx = fmaxf(mx, __shfl_xor(mx, 8));
                mx = fmaxf(mx, p);
                float es = __expf(z0 - mx) + __expf(z1 - mx)
                         + __expf(z2 - mx) + __expf(z3 - mx);
                es += __shfl_xor(es, 1);
                es += __shfl_xor(es, 2);
                es += __shfl_xor(es, 4);
                es += __shfl_xor(es, 8);
                es += __expf(p - mx);
                float loss = __logf(es) + (mx - p);
                loss = (sg < L) ? loss : LOG65;            // masked row => ln(65)
                bool take = (sg < NT - ip) && (fl == 0);   // valid (s,i); one lane per row
                lossacc += take ? wgt[ip - 1] * loss : 0.f;
            }
        }
        lossacc += __shfl_xor(lossacc, 16);
        lossacc += __shfl_xor(lossacc, 32);
        if (lane == 0) wsum[w] = lossacc;
        __syncthreads();                      // also protects Afrag/pos_lds reuse
        if (tid == 0) ws[slot] = wsum[0] + wsum[1] + wsum[2] + wsum[3];
    }
}

// Sum the 2048 per-block partials -> out[0]. One block, no atomics.
__global__ void reduce_k(const float* __restrict__ ws, float* __restrict__ out) {
    const int tid = threadIdx.x;   // 256
    float s = 0.f;
    #pragma unroll
    for (int i = 0; i < NBLK / 256; ++i) s += ws[tid + 256 * i];
    s += __shfl_xor(s, 1);
    s += __shfl_xor(s, 2);
    s += __shfl_xor(s, 4);
    s += __shfl_xor(s, 8);
    s += __shfl_xor(s, 16);
    s += __shfl_xor(s, 32);
    __shared__ float wsum[4];
    if ((tid & 63) == 0) wsum[tid >> 6] = s;
    __syncthreads();
    if (tid == 0) out[0] = wsum[0] + wsum[1] + wsum[2] + wsum[3];
}

extern "C" void kernel_launch(void* const* d_in, const int* in_sizes, int n_in,
                              void* d_out, int out_size, void* d_ws, size_t ws_size,
                              hipStream_t stream) {
    (void)in_sizes; (void)n_in; (void)out_size; (void)ws_size;
    const float* base       = (const float*)d_in[0];
    const float* mce        = (const float*)d_in[1];
    const int*   seq_lens   = (const int*)d_in[2];
    const int*   sample_ids = (const int*)d_in[3];
    float* out = (float*)d_out;
    float* ws  = (float*)d_ws;   // 2048 floats; every tile writes its slot

    cpc_mfma_kernel<<<dim3(NBLK / 2), 256, 0, stream>>>(base, mce, seq_lens, sample_ids, ws);
    reduce_k<<<1, 256, 0, stream>>>(ws, out);
}

// Round 5
// 225.274 us; speedup vs baseline: 1.0145x; 1.0145x over previous
//
#include <hip/hip_runtime.h>
#include <math.h>

#define NB 128
#define NT 512
#define NEDIM 128
#define NNEG 64
#define SCHUNK 32
#define NBLK (NB * (NT / SCHUNK))   // 2048 partial-sum slots

typedef __bf16 bf16x8 __attribute__((ext_vector_type(8)));
typedef float  f32x4  __attribute__((ext_vector_type(4)));

// 512 blocks, each owns 4 consecutive s-chunks of one b (active chunks are a
// prefix of the 4 since seq mask is a prefix). B (negatives) staged once per
// block. Tile loop is software-pipelined: next tile's A loads are issued into
// registers right after this tile's stage-barrier, hiding global-load latency
// behind MFMA + positives + epilogue. Per tile: M=128 (m=4*s_local+(i-1)) x
// N=64 x K=128 bf16 MFMA from xor-swizzled fragment-linear LDS. One ws write
// per tile; no same-address atomics.
__launch_bounds__(256, 2)
__global__ void cpc_mfma_kernel(const float* __restrict__ base,        // (B,T,E)
                                const float* __restrict__ mce,         // (B,T,E,K)
                                const int*  __restrict__ seq_lens,     // (B)
                                const int*  __restrict__ sample_ids,   // (B,NNEG)
                                float* __restrict__ ws)                // (NBLK)
{
    const int j  = blockIdx.x;       // 0..511
    const int b  = j >> 2;           // 4 blocks per b, consecutive -> L2 locality
    const int c0 = (j & 3) * 4;      // first chunk of this block's group of 4
    const int L  = seq_lens[b];
    const float LOG65 = 4.1743873f;
    const float wgt[4] = {1.f/261632.f, 1.f/261120.f, 1.f/260608.f, 1.f/260096.f};

    const int tid  = threadIdx.x;
    const int lane = tid & 63;
    const int w    = tid >> 6;
    const int q    = lane >> 4;
    const int fl   = lane & 15;

    // masked-chunk analytic contribution (all-zero ce rows -> loss = ln(65))
    auto masked_const = [&](int s0) {
        float c = 0.f;
        #pragma unroll
        for (int i = 1; i <= 4; ++i) {
            int hi = min(SCHUNK, (NT - i) - s0);
            if (hi > 0) c += (float)hi * LOG65 * wgt[i - 1];
        }
        return c;
    };

    // Active chunks are a prefix: count them, emit masked tail analytically.
    int rem  = L - c0 * SCHUNK;
    int nact = rem <= 0 ? 0 : min(4, (rem + SCHUNK - 1) >> 5);
    if (tid == 0) {
        for (int c = c0 + nact; c < c0 + 4; ++c)
            ws[b * 16 + c] = masked_const(c * SCHUNK);
    }
    if (nact == 0) return;

    __shared__ __bf16 Afrag[2048 * 8];   // 2048 chunks x 16B
    __shared__ __bf16 Bfrag[1024 * 8];   // 1024 chunks x 16B
    __shared__ float  pos_lds[128];
    __shared__ float  wsum[4];

    const float4* mce4 = (const float4*)mce;   // (b*NT+s)*NEDIM + e -> 4 k values

    // ---- stage B once per block: gather negatives, bf16, fragment-linear ----
    {
        int n = tid & 63;
        int r = sample_ids[b * NNEG + n];
        const float4* srcb = (const float4*)(base + (size_t)r * NEDIM);
        int eb0 = (tid >> 6) * 4;
        #pragma unroll
        for (int it = 0; it < 4; ++it) {
            int eb = eb0 + it;
            float4 v0 = srcb[eb * 2], v1 = srcb[eb * 2 + 1];
            const float* f0 = (const float*)&v0;
            const float* f1 = (const float*)&v1;
            bf16x8 o;
            #pragma unroll
            for (int u = 0; u < 4; ++u) { o[u] = (__bf16)f0[u]; o[4 + u] = (__bf16)f1[u]; }
            *(bf16x8*)(&Bfrag[(eb * 64 + n) * 8]) = o;
        }
    }

    // ---- register prefetch of one A tile (16 float4 per thread) ----
    float4 pf[2][8];
    auto load_pf = [&](int c) {
        int s0l = c * SCHUNK;
        #pragma unroll
        for (int it = 0; it < 2; ++it) {
            int g  = tid + 256 * it;          // 0..511 : (s, e-block)
            int s  = g & 31;
            int eb = g >> 5;                  // e0 = eb*8
            const float4* src = mce4 + (size_t)(b * NT + s0l + s) * NEDIM + eb * 8;
            #pragma unroll
            for (int u = 0; u < 8; ++u) pf[it][u] = src[u];
        }
    };
    load_pf(c0);

    for (int t = 0; t < nact; ++t) {
        const int c    = c0 + t;
        const int s0   = c * SCHUNK;
        const int slot = b * 16 + c;

        // ---- commit prefetched A: transpose k->row, f32->bf16, swizzled ----
        // chunk id = (kstep*8 + mt)*64 + q*16 + flm ; phys = chunk ^ ((chunk>>6)&7)
        #pragma unroll
        for (int it = 0; it < 2; ++it) {
            int g  = tid + 256 * it;
            int s  = g & 31;
            int eb = g >> 5;
            const float* vf = (const float*)pf[it];
            int Cs = (eb >> 2) * 8 + (s >> 2);
            int base_chunk = Cs * 64 + (eb & 3) * 16 + (s & 3) * 4;
            int x = Cs & 7;
            #pragma unroll
            for (int k = 0; k < 4; ++k) {
                int phys = (base_chunk + k) ^ x;
                bf16x8 o;
                #pragma unroll
                for (int u = 0; u < 8; ++u) o[u] = (__bf16)vf[4 * u + k];
                *(bf16x8*)(&Afrag[phys * 8]) = o;
            }
        }
        __syncthreads();                      // A (and B on first tile) visible

        // issue next tile's loads NOW — they fly during MFMA/pos/epilogue
        if (t + 1 < nact) load_pf(c0 + t + 1);

        // ---- MFMA: wave w owns M-tiles {2w,2w+1} x all 4 N-tiles ----
        f32x4 acc[2][4];
        #pragma unroll
        for (int mtl = 0; mtl < 2; ++mtl)
            #pragma unroll
            for (int nt = 0; nt < 4; ++nt) acc[mtl][nt] = (f32x4){0.f, 0.f, 0.f, 0.f};

        #pragma unroll
        for (int kstep = 0; kstep < 4; ++kstep) {
            bf16x8 af[2];
            #pragma unroll
            for (int mtl = 0; mtl < 2; ++mtl) {
                int Cs = kstep * 8 + (2 * w + mtl);
                int phys = (Cs * 64 + lane) ^ (Cs & 7);
                af[mtl] = *(const bf16x8*)(&Afrag[phys * 8]);
            }
            bf16x8 bv[4];
            #pragma unroll
            for (int nt = 0; nt < 4; ++nt) {
                int cB = (kstep * 4 + q) * 64 + nt * 16 + fl;
                bv[nt] = *(const bf16x8*)(&Bfrag[cB * 8]);
            }
            #pragma unroll
            for (int mtl = 0; mtl < 2; ++mtl)
                #pragma unroll
                for (int nt = 0; nt < 4; ++nt)
                    acc[mtl][nt] = __builtin_amdgcn_mfma_f32_16x16x32_bf16(
                        af[mtl], bv[nt], acc[mtl][nt], 0, 0, 0);
        }

        // ---- positives: pos[m] = sum_e A[m][e] * base[b][s+i][e] ----
        {
            int m    = tid >> 1;
            int eh   = tid & 1;              // e-half
            int sloc = m >> 2, ip = (m & 3) + 1;
            int srow = s0 + sloc + ip; if (srow > NT - 1) srow = NT - 1;  // clamp; invalid rows excluded later
            const float4* brow4 = (const float4*)(base + (size_t)(b * NT + srow) * NEDIM + eh * 64);
            int mt = m >> 4, flm = m & 15;
            float psum = 0.f;
            #pragma unroll
            for (int el = 0; el < 8; ++el) {
                int eb = eh * 8 + el;
                int Cs = (eb >> 2) * 8 + mt;
                int phys = (Cs * 64 + (eb & 3) * 16 + flm) ^ (Cs & 7);
                bf16x8 av = *(const bf16x8*)(&Afrag[phys * 8]);
                float4 b0 = brow4[el * 2], b1 = brow4[el * 2 + 1];
                const float* f0 = (const float*)&b0;
                const float* f1 = (const float*)&b1;
                #pragma unroll
                for (int u = 0; u < 4; ++u) {
                    psum = fmaf((float)av[u],     f0[u], psum);
                    psum = fmaf((float)av[4 + u], f1[u], psum);
                }
            }
            psum += __shfl_xor(psum, 1);
            if (eh == 0) pos_lds[m] = psum;
        }
        __syncthreads();                      // pos_lds ready; Afrag reads done

        // ---- epilogue: logsumexp over 65 logits per row, masked mean ----
        float lossacc = 0.f;
        #pragma unroll
        for (int mtl = 0; mtl < 2; ++mtl) {
            #pragma unroll
            for (int r = 0; r < 4; ++r) {
                int m  = w * 32 + mtl * 16 + q * 4 + r;    // C layout: row=(lane>>4)*4+reg
                int sg = s0 + (m >> 2);
                int ip = (m & 3) + 1;
                float z0 = acc[mtl][0][r], z1 = acc[mtl][1][r];
                float z2 = acc[mtl][2][r], z3 = acc[mtl][3][r];
                float p  = pos_lds[m];
                float mx = fmaxf(fmaxf(z0, z1), fmaxf(z2, z3));
                mx = fmaxf(mx, __shfl_xor(mx, 1));
                mx = fmaxf(mx, __shfl_xor(mx, 2));
                mx = fmaxf(mx, __shfl_xor(mx, 4));
                mx = fmaxf(mx, __shfl_xor(mx, 8));
                mx = fmaxf(mx, p);
                float es = __expf(z0 - mx) + __expf(z1 - mx)
                         + __expf(z2 - mx) + __expf(z3 - mx);
                es += __shfl_xor(es, 1);
                es += __shfl_xor(es, 2);
                es += __shfl_xor(es, 4);
                es += __shfl_xor(es, 8);
                es += __expf(p - mx);
                float loss = __logf(es) + (mx - p);
                loss = (sg < L) ? loss : LOG65;            // masked row => ln(65)
                bool take = (sg < NT - ip) && (fl == 0);   // valid (s,i); one lane per row
                lossacc += take ? wgt[ip - 1] * loss : 0.f;
            }
        }
        lossacc += __shfl_xor(lossacc, 16);
        lossacc += __shfl_xor(lossacc, 32);
        if (lane == 0) wsum[w] = lossacc;
        __syncthreads();                      // wsum ready; pos_lds/Afrag reusable
        if (tid == 0) ws[slot] = wsum[0] + wsum[1] + wsum[2] + wsum[3];
    }
}

// Sum the 2048 per-block partials -> out[0]. One block, no atomics.
__global__ void reduce_k(const float* __restrict__ ws, float* __restrict__ out) {
    const int tid = threadIdx.x;   // 256
    float s = 0.f;
    #pragma unroll
    for (int i = 0; i < NBLK / 256; ++i) s += ws[tid + 256 * i];
    s += __shfl_xor(s, 1);
    s += __shfl_xor(s, 2);
    s += __shfl_xor(s, 4);
    s += __shfl_xor(s, 8);
    s += __shfl_xor(s, 16);
    s += __shfl_xor(s, 32);
    __shared__ float wsum[4];
    if ((tid & 63) == 0) wsum[tid >> 6] = s;
    __syncthreads();
    if (tid == 0) out[0] = wsum[0] + wsum[1] + wsum[2] + wsum[3];
}

extern "C" void kernel_launch(void* const* d_in, const int* in_sizes, int n_in,
                              void* d_out, int out_size, void* d_ws, size_t ws_size,
                              hipStream_t stream) {
    (void)in_sizes; (void)n_in; (void)out_size; (void)ws_size;
    const float* base       = (const float*)d_in[0];
    const float* mce        = (const float*)d_in[1];
    const int*   seq_lens   = (const int*)d_in[2];
    const int*   sample_ids = (const int*)d_in[3];
    float* out = (float*)d_out;
    float* ws  = (float*)d_ws;   // 2048 floats; every tile writes its slot

    cpc_mfma_kernel<<<dim3(NBLK / 4), 256, 0, stream>>>(base, mce, seq_lens, sample_ids, ws);
    reduce_k<<<1, 256, 0, stream>>>(ws, out);
}